// Round 3
// baseline (8037.864 us; speedup 1.0000x reference)
//
#include <hip/hip_runtime.h>
#include <math.h>

#define GXD 128
#define GYD 128
#define GZD 32
#define DD  64
#define GCELLS (GXD * GYD * GZD)   // 524288

#define MINX (-20.0f)
#define MINY (-20.0f)
#define MINZ (-2.0f)
#define VOXX (0.3125f)
#define VOXY (0.3125f)
#define VOXZ (0.25f)
#define ELL  (0.5f)
#define EPSV (1e-6f)
#define PIF  (3.14159265358979323846f)

// 19 active taps (the 8 cube corners have d >= ELL -> kval == 0).
// OFF = ox*GYD*GZD + oy*GZD + oz = ox*4096 + oy*32 + oz (valid taps never wrap).
#define NTAP 19
static constexpr int TAP_OX[NTAP]  = {-1,-1,-1,-1,-1, 0, 0, 0, 0, 0, 0, 0, 0, 0, 1, 1, 1, 1, 1};
static constexpr int TAP_OY[NTAP]  = {-1, 0, 0, 0, 1,-1,-1,-1, 0, 0, 0, 1, 1, 1,-1, 0, 0, 0, 1};
static constexpr int TAP_OZ[NTAP]  = { 0,-1, 0, 1, 0,-1, 0, 1,-1, 0, 1,-1, 0, 1, 0,-1, 0, 1, 0};
static constexpr int TAP_OFF[NTAP] = {-4128,-4097,-4096,-4095,-4064,
                                      -33,-32,-31,-1,0,1,31,32,33,
                                      4064,4095,4096,4097,4128};

struct KvArgs { float kv[NTAP]; };

// ---------------------------------------------------------------------------
__device__ __forceinline__ float kval_of(int o) {   // fallback path only
    int ox = o / 9 - 1;
    int oy = (o / 3) % 3 - 1;
    int oz = o % 3 - 1;
    float dx = ox * VOXX, dy = oy * VOXY, dz = oz * VOXZ;
    float d = sqrtf(dx * dx + dy * dy + dz * dz);
    float ang = 2.0f * PIF * d / ELL;
    float v = (1.0f / 3.0f) * (2.0f + cosf(ang)) * (1.0f - d / ELL)
            + (1.0f / (2.0f * PIF)) * sinf(ang);
    v = (d >= ELL) ? 0.0f : v;
    return fminf(fmaxf(v, 0.0f), 1.0f);
}

__device__ __forceinline__ int base_cell(const float* __restrict__ row,
                                         int* cx, int* cy, int* cz) {
    float x = row[0], y = row[1], z = row[2];
    int gx = (int)floorf((x - MINX) / VOXX);
    int gy = (int)floorf((y - MINY) / VOXY);
    int gz = (int)floorf((z - MINZ) / VOXZ);
    gx = min(max(gx, 0), GXD - 1);
    gy = min(max(gy, 0), GYD - 1);
    gz = min(max(gz, 0), GZD - 1);
    *cx = gx; *cy = gy; *cz = gz;
    return (gx * GYD + gy) * GZD + gz;
}

// ===========================================================================
// FAST PATH
// ===========================================================================

// Pass 1: zero the M1/M2 rows of touched base cells (races benign: all write 0)
__global__ void lbki_zero_rows(const float* __restrict__ pc,
                               float* __restrict__ M1,
                               float* __restrict__ M2,
                               int npts) {
    int lane = threadIdx.x & 63;
    int wave = threadIdx.x >> 6;
    int p = blockIdx.x * (blockDim.x >> 6) + wave;
    if (p >= npts) return;
    int cx, cy, cz;
    int g = base_cell(pc + (size_t)p * 67, &cx, &cy, &cz);
    size_t idx = (size_t)g * DD + lane;
    M1[idx] = 0.0f;
    M2[idx] = 0.0f;
}

// Pass 2: scatter per-point raw moments into the BASE cell only.
__global__ void lbki_build(const float* __restrict__ pc,
                           float* __restrict__ M0,
                           float* __restrict__ M1,
                           float* __restrict__ M2,
                           int npts) {
    int lane = threadIdx.x & 63;
    int wave = threadIdx.x >> 6;
    int p = blockIdx.x * (blockDim.x >> 6) + wave;
    if (p >= npts) return;
    const float* row = pc + (size_t)p * 67;
    int cx, cy, cz;
    int g = base_cell(row, &cx, &cy, &cz);
    float f = row[3 + lane];
    size_t idx = (size_t)g * DD + lane;
    atomicAdd(&M1[idx], f);
    atomicAdd(&M2[idx], f * f);
    if (lane == 0) atomicAdd(&M0[g], 1.0f);
}

// Pass 3: 19-tap stencil fused with finalize.
// One wave per cell; lane = feature. All M0 loads batch-issued (invalid taps
// hit the zero sentinel at M0[GCELLS]); M1/M2 loads issued under uniform
// cnt!=0 branches into pre-zeroed regs; FMAs in a separate loop -> one drain.
__global__ __launch_bounds__(256)
void lbki_stencil(const float* __restrict__ M0,
                  const float* __restrict__ M1,
                  const float* __restrict__ M2,
                  const float* __restrict__ mean_map,
                  const float* __restrict__ var_map,
                  const float* __restrict__ conf_map,
                  float* __restrict__ out_mean,
                  float* __restrict__ out_var,
                  float* __restrict__ out_conf,
                  KvArgs ka) {
    int lane = threadIdx.x & 63;
    int wave = threadIdx.x >> 6;

    // bijective XCD swizzle (gridDim.x % 8 == 0): contiguous x-slab per XCD
    unsigned b = blockIdx.x;
    unsigned chunk = gridDim.x >> 3;
    unsigned swz = (b & 7) * chunk + (b >> 3);
    int g = (int)(swz * 4 + wave);

    int cz = g & (GZD - 1);
    int cy = (g >> 5) & (GYD - 1);
    int cx = g >> 12;

    // epilogue data: issue first, used last
    size_t idx = (size_t)g * DD + lane;
    float conf = conf_map[g];
    float mean = mean_map[idx];
    float var  = var_map[idx];

    // ---- A: batch-issue all 19 M0 loads (sentinel for invalid taps) ----
    float cnt[NTAP];
    #pragma unroll
    for (int t = 0; t < NTAP; ++t) {
        bool valid = ((unsigned)(cx + TAP_OX[t]) < (unsigned)GXD) &&
                     ((unsigned)(cy + TAP_OY[t]) < (unsigned)GYD) &&
                     ((unsigned)(cz + TAP_OZ[t]) < (unsigned)GZD);
        int a = valid ? (g + TAP_OFF[t]) : GCELLS;   // M0[GCELLS] == 0
        cnt[t] = M0[a];
    }

    // ---- B: gate on register values; issue M1/M2 loads, defer all uses ----
    float acc_k = 0.0f;
    float kvm[NTAP], m1v[NTAP], m2v[NTAP];
    #pragma unroll
    for (int t = 0; t < NTAP; ++t) {
        bool on = (cnt[t] != 0.0f);                  // wave-uniform
        float kt = on ? ka.kv[t] : 0.0f;
        kvm[t] = kt;
        acc_k += kt * cnt[t];
        m1v[t] = 0.0f;
        m2v[t] = 0.0f;
        if (on) {
            size_t ni = (size_t)(g + TAP_OFF[t]) * DD + lane;
            m1v[t] = M1[ni];
            m2v[t] = M2[ni];
        }
    }

    // ---- C: accumulate (single waitcnt drain before first use) ----
    float acc_y = 0.0f, acc_s = 0.0f;
    #pragma unroll
    for (int t = 0; t < NTAP; ++t) {
        acc_y += kvm[t] * m1v[t];
        acc_s += kvm[t] * m2v[t];
    }

    // ---- finalize ----
    float kb    = acc_k;
    float ybar  = acc_y / (kb + EPSV);
    float Sbar  = acc_s - 2.0f * ybar * acc_y + ybar * ybar * kb;
    float denom = conf + kb + EPSV;
    float dm    = ybar - mean;
    float scal  = conf * kb / denom;

    out_mean[idx] = (conf * mean + kb * ybar) / denom;
    out_var[idx]  = var + Sbar + scal * dm * dm;
    if (lane == 0) out_conf[g] = conf + kb;
}

// ===========================================================================
// FALLBACK PATH (round-1 kernels, used only if workspace is too small)
// ===========================================================================
__global__ void lbki_accum(const float* __restrict__ pc,
                           float* __restrict__ y_sum,
                           float* __restrict__ sq_sum,
                           float* __restrict__ k_bar,
                           int npts) {
    __shared__ float kval_s[27];
    if (threadIdx.x < 27) kval_s[threadIdx.x] = kval_of(threadIdx.x);
    __syncthreads();

    int lane = threadIdx.x & 63;
    int wave = threadIdx.x >> 6;
    int p = blockIdx.x * (blockDim.x >> 6) + wave;
    if (p >= npts) return;

    const float* row = pc + (size_t)p * 67;
    int gx, gy, gz;
    base_cell(row, &gx, &gy, &gz);
    float f = row[3 + lane];
    float ff = f * f;

    #pragma unroll
    for (int o = 0; o < 27; ++o) {
        float kv = kval_s[o];
        if (kv <= 0.0f) continue;
        int nx = gx + (o / 9) - 1;
        int ny = gy + ((o / 3) % 3) - 1;
        int nz = gz + (o % 3) - 1;
        if ((unsigned)nx >= (unsigned)GXD) continue;
        if ((unsigned)ny >= (unsigned)GYD) continue;
        if ((unsigned)nz >= (unsigned)GZD) continue;
        size_t g = ((size_t)nx * GYD + ny) * GZD + nz;
        atomicAdd(&y_sum[g * DD + lane], kv * f);
        atomicAdd(&sq_sum[g * DD + lane], kv * ff);
        if (lane == 0) atomicAdd(&k_bar[g], kv);
    }
}

__global__ void lbki_finalize(const float* __restrict__ mean_map,
                              const float* __restrict__ var_map,
                              const float* __restrict__ conf_map,
                              float* __restrict__ out_mean,
                              float* __restrict__ out_var,
                              float* __restrict__ out_conf) {
    int lane = threadIdx.x & 63;
    int wave = threadIdx.x >> 6;
    int g = blockIdx.x * (blockDim.x >> 6) + wave;
    if (g >= GCELLS) return;

    float kb   = out_conf[g];
    float conf = conf_map[g];

    size_t idx = (size_t)g * DD + lane;
    float ys   = out_mean[idx];
    float sq   = out_var[idx];
    float mean = mean_map[idx];
    float var  = var_map[idx];

    float ybar  = ys / (kb + EPSV);
    float Sbar  = sq - 2.0f * ybar * ys + ybar * ybar * kb;
    float denom = conf + kb + EPSV;
    float dm    = ybar - mean;
    float scal  = conf * kb / denom;

    out_mean[idx] = (conf * mean + kb * ybar) / denom;
    out_var[idx]  = var + Sbar + scal * dm * dm;
    if (lane == 0) out_conf[g] = conf + kb;
}

// ===========================================================================
extern "C" void kernel_launch(void* const* d_in, const int* in_sizes, int n_in,
                              void* d_out, int out_size, void* d_ws, size_t ws_size,
                              hipStream_t stream) {
    const float* mean_map = (const float*)d_in[0];
    const float* var_map  = (const float*)d_in[1];
    const float* conf_map = (const float*)d_in[2];
    const float* pc       = (const float*)d_in[3];
    int npts = in_sizes[3] / 67;

    float* out      = (float*)d_out;
    float* out_mean = out;
    float* out_var  = out + (size_t)GCELLS * DD;
    float* out_conf = out + (size_t)2 * GCELLS * DD;

    // layout: M0 [GCELLS + 64 pad incl. zero sentinel] | M1 [G*D] | M2 [G*D]
    const size_t M0_STRIDE = (size_t)GCELLS + 64;
    const size_t WS_NEEDED = (M0_STRIDE + 2 * (size_t)GCELLS * DD) * sizeof(float);

    if (ws_size >= WS_NEEDED) {
        float* M0 = (float*)d_ws;
        float* M1 = M0 + M0_STRIDE;
        float* M2 = M1 + (size_t)GCELLS * DD;

        // zero M0 + sentinel pad
        hipMemsetAsync(M0, 0, M0_STRIDE * sizeof(float), stream);

        int wpb = 4;
        int pblocks = (npts + wpb - 1) / wpb;
        lbki_zero_rows<<<pblocks, 256, 0, stream>>>(pc, M1, M2, npts);
        lbki_build<<<pblocks, 256, 0, stream>>>(pc, M0, M1, M2, npts);

        // host-side kv for the 19 active taps (double precision, cast to f32)
        KvArgs ka;
        for (int t = 0; t < NTAP; ++t) {
            double dx = TAP_OX[t] * (double)VOXX;
            double dy = TAP_OY[t] * (double)VOXY;
            double dz = TAP_OZ[t] * (double)VOXZ;
            double d  = sqrt(dx * dx + dy * dy + dz * dz);
            double ang = 2.0 * (double)PIF * d / (double)ELL;
            double v = (1.0 / 3.0) * (2.0 + cos(ang)) * (1.0 - d / (double)ELL)
                     + (1.0 / (2.0 * (double)PIF)) * sin(ang);
            if (d >= (double)ELL) v = 0.0;
            v = v < 0.0 ? 0.0 : (v > 1.0 ? 1.0 : v);
            ka.kv[t] = (float)v;
        }

        int sblocks = GCELLS / 4;   // 131072, % 8 == 0 for the swizzle
        lbki_stencil<<<sblocks, 256, 0, stream>>>(M0, M1, M2,
                                                  mean_map, var_map, conf_map,
                                                  out_mean, out_var, out_conf, ka);
    } else {
        hipMemsetAsync(d_out, 0, (size_t)out_size * sizeof(float), stream);
        int wpb = 4;
        int blocks = (npts + wpb - 1) / wpb;
        lbki_accum<<<blocks, 256, 0, stream>>>(pc, out_mean, out_var, out_conf, npts);
        int fblocks = GCELLS / 4;
        lbki_finalize<<<fblocks, 256, 0, stream>>>(mean_map, var_map, conf_map,
                                                   out_mean, out_var, out_conf);
    }
}

// Round 4
// 418.113 us; speedup vs baseline: 19.2241x; 19.2241x over previous
//
#include <hip/hip_runtime.h>
#include <math.h>

#define GXD 128
#define GYD 128
#define GZD 32
#define DD  64
#define GCELLS (GXD * GYD * GZD)   // 524288

#define MINX (-20.0f)
#define MINY (-20.0f)
#define MINZ (-2.0f)
#define VOXX (0.3125f)
#define VOXY (0.3125f)
#define VOXZ (0.25f)
#define ELL  (0.5f)
#define EPSV (1e-6f)
#define PIF  (3.14159265358979323846f)

// 19 active taps (the 8 cube corners have d >= ELL -> kval == 0).
// OFF = ox*4096 + oy*32 + oz (valid taps never wrap across dims).
#define NTAP 19
static constexpr int TAP_OX[NTAP]  = {-1,-1,-1,-1,-1, 0, 0, 0, 0, 0, 0, 0, 0, 0, 1, 1, 1, 1, 1};
static constexpr int TAP_OY[NTAP]  = {-1, 0, 0, 0, 1,-1,-1,-1, 0, 0, 0, 1, 1, 1,-1, 0, 0, 0, 1};
static constexpr int TAP_OZ[NTAP]  = { 0,-1, 0, 1, 0,-1, 0, 1,-1, 0, 1,-1, 0, 1, 0,-1, 0, 1, 0};
static constexpr int TAP_OFF[NTAP] = {-4128,-4097,-4096,-4095,-4064,
                                      -33,-32,-31,-1,0,1,31,32,33,
                                      4064,4095,4096,4097,4128};

struct KvArgs { float kv[NTAP]; };

// ---------------------------------------------------------------------------
__device__ __forceinline__ float kval_of(int o) {   // fallback path only
    int ox = o / 9 - 1;
    int oy = (o / 3) % 3 - 1;
    int oz = o % 3 - 1;
    float dx = ox * VOXX, dy = oy * VOXY, dz = oz * VOXZ;
    float d = sqrtf(dx * dx + dy * dy + dz * dz);
    float ang = 2.0f * PIF * d / ELL;
    float v = (1.0f / 3.0f) * (2.0f + cosf(ang)) * (1.0f - d / ELL)
            + (1.0f / (2.0f * PIF)) * sinf(ang);
    v = (d >= ELL) ? 0.0f : v;
    return fminf(fmaxf(v, 0.0f), 1.0f);
}

__device__ __forceinline__ int base_cell(const float* __restrict__ row,
                                         int* cx, int* cy, int* cz) {
    float x = row[0], y = row[1], z = row[2];
    int gx = (int)floorf((x - MINX) / VOXX);
    int gy = (int)floorf((y - MINY) / VOXY);
    int gz = (int)floorf((z - MINZ) / VOXZ);
    gx = min(max(gx, 0), GXD - 1);
    gy = min(max(gy, 0), GYD - 1);
    gz = min(max(gz, 0), GZD - 1);
    *cx = gx; *cy = gy; *cz = gz;
    return (gx * GYD + gy) * GZD + gz;
}

// ===========================================================================
// FAST PATH  — workspace layout:
//   M0 : GCELLS + 64      (cell counts; slot [GCELLS] is the zero sentinel)
//   M1 : GCELLS*DD + 64   (sum f;  row  [GCELLS] is the zero sentinel row)
//   M2 : GCELLS*DD + 64   (sum f^2; row [GCELLS] is the zero sentinel row)
// ===========================================================================

// Pass 1: zero the M1/M2 rows of touched base cells (races benign: all write 0)
__global__ void lbki_zero_rows(const float* __restrict__ pc,
                               float* __restrict__ M1,
                               float* __restrict__ M2,
                               int npts) {
    int lane = threadIdx.x & 63;
    int wave = threadIdx.x >> 6;
    int p = blockIdx.x * (blockDim.x >> 6) + wave;
    if (p >= npts) return;
    int cx, cy, cz;
    int g = base_cell(pc + (size_t)p * 67, &cx, &cy, &cz);
    size_t idx = (size_t)g * DD + lane;
    M1[idx] = 0.0f;
    M2[idx] = 0.0f;
}

// Pass 2: scatter per-point raw moments into the BASE cell only.
__global__ void lbki_build(const float* __restrict__ pc,
                           float* __restrict__ M0,
                           float* __restrict__ M1,
                           float* __restrict__ M2,
                           int npts) {
    int lane = threadIdx.x & 63;
    int wave = threadIdx.x >> 6;
    int p = blockIdx.x * (blockDim.x >> 6) + wave;
    if (p >= npts) return;
    const float* row = pc + (size_t)p * 67;
    int cx, cy, cz;
    int g = base_cell(row, &cx, &cy, &cz);
    float f = row[3 + lane];
    size_t idx = (size_t)g * DD + lane;
    atomicAdd(&M1[idx], f);
    atomicAdd(&M2[idx], f * f);
    if (lane == 0) atomicAdd(&M0[g], 1.0f);
}

// Pass 3: 19-tap stencil fused with finalize. One wave per cell; lane=feature.
// NO control flow: gating is done by cndmask'ing load INDICES to zeroed
// sentinels. Three straight unrolled loops -> batched loads, no spills.
__global__ __launch_bounds__(256)
void lbki_stencil(const float* __restrict__ M0,
                  const float* __restrict__ M1,
                  const float* __restrict__ M2,
                  const float* __restrict__ mean_map,
                  const float* __restrict__ var_map,
                  const float* __restrict__ conf_map,
                  float* __restrict__ out_mean,
                  float* __restrict__ out_var,
                  float* __restrict__ out_conf,
                  KvArgs ka) {
    int lane = threadIdx.x & 63;
    int wave = threadIdx.x >> 6;

    // bijective XCD swizzle (gridDim.x % 8 == 0): contiguous x-slab per XCD
    unsigned b = blockIdx.x;
    unsigned chunk = gridDim.x >> 3;
    unsigned swz = (b & 7) * chunk + (b >> 3);
    int g = (int)(swz * 4u + wave);

    int cz = g & (GZD - 1);
    int cy = (g >> 5) & (GYD - 1);
    int cx = g >> 12;

    // epilogue data: issue first, used last
    size_t idx = (size_t)g * DD + lane;
    float conf = conf_map[g];
    float mean = mean_map[idx];
    float var  = var_map[idx];

    // ---- A: batch-issue all 19 M0 loads (index-select, no branches) ----
    float cnt[NTAP];
    #pragma unroll
    for (int t = 0; t < NTAP; ++t) {
        bool valid = ((unsigned)(cx + TAP_OX[t]) < (unsigned)GXD) &&
                     ((unsigned)(cy + TAP_OY[t]) < (unsigned)GYD) &&
                     ((unsigned)(cz + TAP_OZ[t]) < (unsigned)GZD);
        unsigned a = valid ? (unsigned)(g + TAP_OFF[t]) : (unsigned)GCELLS;
        cnt[t] = M0[a];
    }

    // ---- B: acc_k + batch-issue 38 M1/M2 loads (shared per-tap index) ----
    const unsigned row0 = (unsigned)g * DD + (unsigned)lane;
    const unsigned srow = (unsigned)GCELLS * DD + (unsigned)lane;  // zero row
    float acc_k = 0.0f;
    float m1v[NTAP], m2v[NTAP];
    #pragma unroll
    for (int t = 0; t < NTAP; ++t) {
        acc_k += ka.kv[t] * cnt[t];              // cnt==0 for invalid taps
        bool on = (cnt[t] != 0.0f);
        unsigned ni = on ? (row0 + TAP_OFF[t] * DD) : srow;
        m1v[t] = M1[ni];
        m2v[t] = M2[ni];
    }

    // ---- C: accumulate (single drain; zeros flow through for off taps) ----
    float acc_y = 0.0f, acc_s = 0.0f;
    #pragma unroll
    for (int t = 0; t < NTAP; ++t) {
        acc_y += ka.kv[t] * m1v[t];
        acc_s += ka.kv[t] * m2v[t];
    }

    // ---- finalize ----
    float kb    = acc_k;
    float ybar  = acc_y / (kb + EPSV);
    float Sbar  = acc_s - 2.0f * ybar * acc_y + ybar * ybar * kb;
    float denom = conf + kb + EPSV;
    float dm    = ybar - mean;
    float scal  = conf * kb / denom;

    out_mean[idx] = (conf * mean + kb * ybar) / denom;
    out_var[idx]  = var + Sbar + scal * dm * dm;
    if (lane == 0) out_conf[g] = conf + kb;
}

// ===========================================================================
// FALLBACK PATH (round-1 kernels, used only if workspace is too small)
// ===========================================================================
__global__ void lbki_accum(const float* __restrict__ pc,
                           float* __restrict__ y_sum,
                           float* __restrict__ sq_sum,
                           float* __restrict__ k_bar,
                           int npts) {
    __shared__ float kval_s[27];
    if (threadIdx.x < 27) kval_s[threadIdx.x] = kval_of(threadIdx.x);
    __syncthreads();

    int lane = threadIdx.x & 63;
    int wave = threadIdx.x >> 6;
    int p = blockIdx.x * (blockDim.x >> 6) + wave;
    if (p >= npts) return;

    const float* row = pc + (size_t)p * 67;
    int gx, gy, gz;
    base_cell(row, &gx, &gy, &gz);
    float f = row[3 + lane];
    float ff = f * f;

    #pragma unroll
    for (int o = 0; o < 27; ++o) {
        float kv = kval_s[o];
        if (kv <= 0.0f) continue;
        int nx = gx + (o / 9) - 1;
        int ny = gy + ((o / 3) % 3) - 1;
        int nz = gz + (o % 3) - 1;
        if ((unsigned)nx >= (unsigned)GXD) continue;
        if ((unsigned)ny >= (unsigned)GYD) continue;
        if ((unsigned)nz >= (unsigned)GZD) continue;
        size_t g = ((size_t)nx * GYD + ny) * GZD + nz;
        atomicAdd(&y_sum[g * DD + lane], kv * f);
        atomicAdd(&sq_sum[g * DD + lane], kv * ff);
        if (lane == 0) atomicAdd(&k_bar[g], kv);
    }
}

__global__ void lbki_finalize(const float* __restrict__ mean_map,
                              const float* __restrict__ var_map,
                              const float* __restrict__ conf_map,
                              float* __restrict__ out_mean,
                              float* __restrict__ out_var,
                              float* __restrict__ out_conf) {
    int lane = threadIdx.x & 63;
    int wave = threadIdx.x >> 6;
    int g = blockIdx.x * (blockDim.x >> 6) + wave;
    if (g >= GCELLS) return;

    float kb   = out_conf[g];
    float conf = conf_map[g];

    size_t idx = (size_t)g * DD + lane;
    float ys   = out_mean[idx];
    float sq   = out_var[idx];
    float mean = mean_map[idx];
    float var  = var_map[idx];

    float ybar  = ys / (kb + EPSV);
    float Sbar  = sq - 2.0f * ybar * ys + ybar * ybar * kb;
    float denom = conf + kb + EPSV;
    float dm    = ybar - mean;
    float scal  = conf * kb / denom;

    out_mean[idx] = (conf * mean + kb * ybar) / denom;
    out_var[idx]  = var + Sbar + scal * dm * dm;
    if (lane == 0) out_conf[g] = conf + kb;
}

// ===========================================================================
extern "C" void kernel_launch(void* const* d_in, const int* in_sizes, int n_in,
                              void* d_out, int out_size, void* d_ws, size_t ws_size,
                              hipStream_t stream) {
    const float* mean_map = (const float*)d_in[0];
    const float* var_map  = (const float*)d_in[1];
    const float* conf_map = (const float*)d_in[2];
    const float* pc       = (const float*)d_in[3];
    int npts = in_sizes[3] / 67;

    float* out      = (float*)d_out;
    float* out_mean = out;
    float* out_var  = out + (size_t)GCELLS * DD;
    float* out_conf = out + (size_t)2 * GCELLS * DD;

    const size_t M0_ELEMS = (size_t)GCELLS + 64;        // + sentinel slot(s)
    const size_t M_ELEMS  = (size_t)GCELLS * DD + 64;   // + sentinel row
    const size_t WS_NEEDED = (M0_ELEMS + 2 * M_ELEMS) * sizeof(float);

    if (ws_size >= WS_NEEDED) {
        float* M0 = (float*)d_ws;
        float* M1 = M0 + M0_ELEMS;
        float* M2 = M1 + M_ELEMS;

        // zero M0 (+ its sentinel pad) and the two sentinel rows
        hipMemsetAsync(M0, 0, M0_ELEMS * sizeof(float), stream);
        hipMemsetAsync(M1 + (size_t)GCELLS * DD, 0, 64 * sizeof(float), stream);
        hipMemsetAsync(M2 + (size_t)GCELLS * DD, 0, 64 * sizeof(float), stream);

        int wpb = 4;
        int pblocks = (npts + wpb - 1) / wpb;
        lbki_zero_rows<<<pblocks, 256, 0, stream>>>(pc, M1, M2, npts);
        lbki_build<<<pblocks, 256, 0, stream>>>(pc, M0, M1, M2, npts);

        // host-side kv for the 19 active taps
        KvArgs ka;
        for (int t = 0; t < NTAP; ++t) {
            double dx = TAP_OX[t] * (double)VOXX;
            double dy = TAP_OY[t] * (double)VOXY;
            double dz = TAP_OZ[t] * (double)VOXZ;
            double d  = sqrt(dx * dx + dy * dy + dz * dz);
            double ang = 2.0 * (double)PIF * d / (double)ELL;
            double v = (1.0 / 3.0) * (2.0 + cos(ang)) * (1.0 - d / (double)ELL)
                     + (1.0 / (2.0 * (double)PIF)) * sin(ang);
            if (d >= (double)ELL) v = 0.0;
            v = v < 0.0 ? 0.0 : (v > 1.0 ? 1.0 : v);
            ka.kv[t] = (float)v;
        }

        int sblocks = GCELLS / 4;   // 131072, % 8 == 0 for the swizzle
        lbki_stencil<<<sblocks, 256, 0, stream>>>(M0, M1, M2,
                                                  mean_map, var_map, conf_map,
                                                  out_mean, out_var, out_conf, ka);
    } else {
        hipMemsetAsync(d_out, 0, (size_t)out_size * sizeof(float), stream);
        int wpb = 4;
        int blocks = (npts + wpb - 1) / wpb;
        lbki_accum<<<blocks, 256, 0, stream>>>(pc, out_mean, out_var, out_conf, npts);
        int fblocks = GCELLS / 4;
        lbki_finalize<<<fblocks, 256, 0, stream>>>(mean_map, var_map, conf_map,
                                                   out_mean, out_var, out_conf);
    }
}